// Round 1
// baseline (199.377 us; speedup 1.0000x reference)
//
#include <hip/hip_runtime.h>

#define BB 4096
#define TT 10
#define SS 301
#define HH 5
#define OO 3

__device__ __forceinline__ float sigmoidf_fast(float x) {
    return 1.0f / (1.0f + __expf(-x));
}
// overflow-safe tanh: 1 - 2/(e^{2x}+1); e->inf gives 1, e->0 gives -1
__device__ __forceinline__ float tanhf_fast(float x) {
    return 1.0f - 2.0f / (__expf(2.0f * x) + 1.0f);
}

__global__ __launch_bounds__(256) void gru_kernel(
    const float* __restrict__ x,
    const float* __restrict__ w_ih,
    const float* __restrict__ w_hh,
    const float* __restrict__ b_ih,
    const float* __restrict__ b_hh,
    const float* __restrict__ fc_w,
    const float* __restrict__ fc_b,
    float* __restrict__ out)
{
    const int n = blockIdx.x * blockDim.x + threadIdx.x;
    const int b = n / SS;
    const int s = n - b * SS;
    if (b >= BB) return;

    // Wave-uniform weights: compiler emits scalar loads.
    float wih[3 * HH];
    float whh[3 * HH][HH];
    float brz[2 * HH];   // merged b_ih + b_hh for r,z gates
    float bin[HH];       // b_ih for n gate (outside r*)
    float bhn[HH];       // b_hh for n gate (inside r*)

    #pragma unroll
    for (int g = 0; g < 2 * HH; ++g) brz[g] = b_ih[g] + b_hh[g];
    #pragma unroll
    for (int j = 0; j < HH; ++j) {
        bin[j] = b_ih[2 * HH + j];
        bhn[j] = b_hh[2 * HH + j];
    }
    #pragma unroll
    for (int g = 0; g < 3 * HH; ++g) {
        wih[g] = w_ih[g];   // I == 1
        #pragma unroll
        for (int k = 0; k < HH; ++k) whh[g][k] = w_hh[g * HH + k];
    }

    // Preload all 10 inputs for this sample (coalesced across the wave per t).
    float xt[TT];
    const float* xp = x + (size_t)b * (TT * SS) + s;
    #pragma unroll
    for (int t = 0; t < TT; ++t) xt[t] = xp[t * SS];

    float h[HH];
    #pragma unroll
    for (int j = 0; j < HH; ++j) h[j] = 0.0f;

    #pragma unroll
    for (int t = 0; t < TT; ++t) {
        float hn[HH];
        #pragma unroll
        for (int j = 0; j < HH; ++j) {
            float ar  = __fmaf_rn(xt[t], wih[j],          brz[j]);
            float az  = __fmaf_rn(xt[t], wih[HH + j],     brz[HH + j]);
            float ain = __fmaf_rn(xt[t], wih[2 * HH + j], bin[j]);
            float ahn = bhn[j];
            #pragma unroll
            for (int k = 0; k < HH; ++k) {
                ar  = __fmaf_rn(whh[j][k],          h[k], ar);
                az  = __fmaf_rn(whh[HH + j][k],     h[k], az);
                ahn = __fmaf_rn(whh[2 * HH + j][k], h[k], ahn);
            }
            float r  = sigmoidf_fast(ar);
            float z  = sigmoidf_fast(az);
            float nv = tanhf_fast(__fmaf_rn(r, ahn, ain));
            // (1-z)*nv + z*h = z*(h - nv) + nv
            hn[j] = __fmaf_rn(z, h[j] - nv, nv);
        }
        #pragma unroll
        for (int j = 0; j < HH; ++j) h[j] = hn[j];
    }

    // y = fc(h); out[(b*O + o)*S + s]
    float* op = out + (size_t)b * (OO * SS) + s;
    #pragma unroll
    for (int o = 0; o < OO; ++o) {
        float y = fc_b[o];
        #pragma unroll
        for (int k = 0; k < HH; ++k) y = __fmaf_rn(fc_w[o * HH + k], h[k], y);
        op[o * SS] = y;
    }
}

extern "C" void kernel_launch(void* const* d_in, const int* in_sizes, int n_in,
                              void* d_out, int out_size, void* d_ws, size_t ws_size,
                              hipStream_t stream) {
    const float* x    = (const float*)d_in[0];
    const float* w_ih = (const float*)d_in[1];
    const float* w_hh = (const float*)d_in[2];
    const float* b_ih = (const float*)d_in[3];
    const float* b_hh = (const float*)d_in[4];
    const float* fc_w = (const float*)d_in[5];
    const float* fc_b = (const float*)d_in[6];
    float* out = (float*)d_out;

    const int N = BB * SS;                 // 1,232,896
    const int block = 256;
    const int grid = (N + block - 1) / block;  // 4816 exactly
    gru_kernel<<<grid, block, 0, stream>>>(x, w_ih, w_hh, b_ih, b_hh, fc_w, fc_b, out);
}

// Round 2
// 157.239 us; speedup vs baseline: 1.2680x; 1.2680x over previous
//
#include <hip/hip_runtime.h>

#define BB 4096
#define TT 10
#define SS 301
#define HH 5
#define OO 3

// Raw v_rcp_f32 (~1 ulp) instead of IEEE div sequence (~10 instr).
__device__ __forceinline__ float fast_rcp(float x) {
    return __builtin_amdgcn_rcpf(x);
}
__device__ __forceinline__ float sigmoidf_fast(float x) {
    // 1/(1+e^-x); rcp(inf)=0 handles the saturated tail.
    return fast_rcp(1.0f + __expf(-x));
}
// overflow-safe tanh: 1 - 2/(e^{2x}+1); e->inf gives 1, e->0 gives -1
__device__ __forceinline__ float tanhf_fast(float x) {
    return __fmaf_rn(-2.0f, fast_rcp(__expf(2.0f * x) + 1.0f), 1.0f);
}

__global__ __launch_bounds__(256) void gru_kernel(
    const float* __restrict__ x,
    const float* __restrict__ w_ih,
    const float* __restrict__ w_hh,
    const float* __restrict__ b_ih,
    const float* __restrict__ b_hh,
    const float* __restrict__ fc_w,
    const float* __restrict__ fc_b,
    float* __restrict__ out)
{
    const int n = blockIdx.x * blockDim.x + threadIdx.x;
    const int b = n / SS;
    const int s = n - b * SS;
    if (b >= BB) return;

    // Wave-uniform weights: compiler emits scalar loads.
    float wih[3 * HH];
    float whh[3 * HH][HH];
    float brz[2 * HH];   // merged b_ih + b_hh for r,z gates
    float bin[HH];       // b_ih for n gate (outside r*)
    float bhn[HH];       // b_hh for n gate (inside r*)

    #pragma unroll
    for (int g = 0; g < 2 * HH; ++g) brz[g] = b_ih[g] + b_hh[g];
    #pragma unroll
    for (int j = 0; j < HH; ++j) {
        bin[j] = b_ih[2 * HH + j];
        bhn[j] = b_hh[2 * HH + j];
    }
    #pragma unroll
    for (int g = 0; g < 3 * HH; ++g) {
        wih[g] = w_ih[g];   // I == 1
        #pragma unroll
        for (int k = 0; k < HH; ++k) whh[g][k] = w_hh[g * HH + k];
    }

    // Preload all 10 inputs for this sample (coalesced across the wave per t).
    float xt[TT];
    const float* xp = x + (size_t)b * (TT * SS) + s;
    #pragma unroll
    for (int t = 0; t < TT; ++t) xt[t] = xp[t * SS];

    float h[HH];
    #pragma unroll
    for (int j = 0; j < HH; ++j) h[j] = 0.0f;

    #pragma unroll
    for (int t = 0; t < TT; ++t) {
        float hn[HH];
        #pragma unroll
        for (int j = 0; j < HH; ++j) {
            float ar  = __fmaf_rn(xt[t], wih[j],          brz[j]);
            float az  = __fmaf_rn(xt[t], wih[HH + j],     brz[HH + j]);
            float ain = __fmaf_rn(xt[t], wih[2 * HH + j], bin[j]);
            float ahn = bhn[j];
            #pragma unroll
            for (int k = 0; k < HH; ++k) {
                ar  = __fmaf_rn(whh[j][k],          h[k], ar);
                az  = __fmaf_rn(whh[HH + j][k],     h[k], az);
                ahn = __fmaf_rn(whh[2 * HH + j][k], h[k], ahn);
            }
            float r  = sigmoidf_fast(ar);
            float z  = sigmoidf_fast(az);
            float nv = tanhf_fast(__fmaf_rn(r, ahn, ain));
            // (1-z)*nv + z*h = z*(h - nv) + nv
            hn[j] = __fmaf_rn(z, h[j] - nv, nv);
        }
        #pragma unroll
        for (int j = 0; j < HH; ++j) h[j] = hn[j];
    }

    // y = fc(h); out[(b*O + o)*S + s]
    float* op = out + (size_t)b * (OO * SS) + s;
    #pragma unroll
    for (int o = 0; o < OO; ++o) {
        float y = fc_b[o];
        #pragma unroll
        for (int k = 0; k < HH; ++k) y = __fmaf_rn(fc_w[o * HH + k], h[k], y);
        op[o * SS] = y;
    }
}

extern "C" void kernel_launch(void* const* d_in, const int* in_sizes, int n_in,
                              void* d_out, int out_size, void* d_ws, size_t ws_size,
                              hipStream_t stream) {
    const float* x    = (const float*)d_in[0];
    const float* w_ih = (const float*)d_in[1];
    const float* w_hh = (const float*)d_in[2];
    const float* b_ih = (const float*)d_in[3];
    const float* b_hh = (const float*)d_in[4];
    const float* fc_w = (const float*)d_in[5];
    const float* fc_b = (const float*)d_in[6];
    float* out = (float*)d_out;

    const int N = BB * SS;                 // 1,232,896
    const int block = 256;
    const int grid = (N + block - 1) / block;  // 4816 exactly
    gru_kernel<<<grid, block, 0, stream>>>(x, w_ih, w_hh, b_ih, b_hh, fc_w, fc_b, out);
}